// Round 5
// baseline (347.943 us; speedup 1.0000x reference)
//
#include <hip/hip_runtime.h>

// Problem constants (CRF: B=256 seqs, M=1024 steps, D=128 feat, N=26 labels)
#define CB 256
#define CM 1024
#define CD 128
#define CN 26

typedef __attribute__((ext_vector_type(2))) float f32x2;

__device__ inline float rfl_f(float x) {
    return __int_as_float(__builtin_amdgcn_readfirstlane(__float_as_int(x)));
}
__device__ inline float rdl_f(float x, int lane) {
#if __has_builtin(__builtin_amdgcn_readlane)
    return __int_as_float(__builtin_amdgcn_readlane(__float_as_int(x), lane));
#else
    return __shfl(x, lane, 64);
#endif
}
__device__ inline float fexp2(float x) {
#if __has_builtin(__builtin_amdgcn_exp2f)
    return __builtin_amdgcn_exp2f(x);
#else
    return exp2f(x);
#endif
}
__device__ inline float flog2(float x) {
#if __has_builtin(__builtin_amdgcn_logf)
    return __builtin_amdgcn_logf(x);
#else
    return log2f(x);
#endif
}
__device__ inline f32x2 fma2(f32x2 a, f32x2 b, f32x2 c) {
#if __has_builtin(__builtin_elementwise_fma)
    return __builtin_elementwise_fma(a, b, c);  // -> v_pk_fma_f32
#else
    f32x2 r;
    r[0] = fmaf(a[0], b[0], c[0]);
    r[1] = fmaf(a[1], b[1], c[1]);
    return r;
#endif
}

// ---------------------------------------------------------------------------
// Kernel 1: emissions E[r, a] = log2(e) * dot(X[r, :], W[a, :])
//   + fused unnorm term: usum = sum_i e[i,y_i] + sum_i T[y_{i-1},y_i]
// Block = 256 threads = 256 rows.
// X: LDS-staged in coalesced 256-row x 32-col slabs.
// W: wave-uniform global reads -> s_load via K$ (round-3 win, kept).
// Round-4 change: float2 accumulators + packed fma so the compiler emits
// v_pk_fma_f32 (2 FMAs/instr) — emit is VALU-issue-bound (3328 scalar
// FMAs/thread = ~44 us/CU issue floor); packed math halves it.
// ---------------------------------------------------------------------------
__global__ __launch_bounds__(256) void emit_kernel(
    const float* __restrict__ X, const float* __restrict__ W,
    const int* __restrict__ labels, const float* __restrict__ T,
    float* __restrict__ E, float* __restrict__ out) {
    __shared__ float Xs[256 * 36];  // 36864 B, pitch 36 floats (16B-aligned)
    __shared__ float rsum[4];

    const int t = threadIdx.x;
    const int R0 = blockIdx.x * 256;

    f32x2 acc2[CN];  // even/odd-j partial sums, combined at the end
#pragma unroll
    for (int a = 0; a < CN; ++a) acc2[a] = (f32x2){0.f, 0.f};

    for (int c = 0; c < 4; ++c) {  // four 32-col slabs of D=128
        if (c) __syncthreads();    // protect Xs reuse (readers done)
#pragma unroll
        for (int q = 0; q < 8; ++q) {
            int g = q * 256 + t;
            int row = g >> 3, cv = g & 7;  // 8 float4 per row-slab
            *reinterpret_cast<float4*>(&Xs[row * 36 + cv * 4]) =
                *reinterpret_cast<const float4*>(
                    X + (size_t)(R0 + row) * CD + c * 32 + cv * 4);
        }
        __syncthreads();

        f32x2 xv[16];  // this thread's 32-col row slab -> registers once
#pragma unroll
        for (int jj = 0; jj < 16; ++jj)
            xv[jj] = *reinterpret_cast<const f32x2*>(&Xs[t * 36 + jj * 2]);

#pragma unroll
        for (int a = 0; a < CN; ++a) {
            // wave-uniform -> s_load pairs from K$
            const f32x2* wp =
                reinterpret_cast<const f32x2*>(W + a * CD + c * 32);
#pragma unroll
            for (int jj = 0; jj < 16; ++jj)
                acc2[a] = fma2(xv[jj], wp[jj], acc2[a]);
        }
    }

    float acc[CN];
#pragma unroll
    for (int a = 0; a < CN; ++a) acc[a] = acc2[a][0] + acc2[a][1];

    // Store E pre-scaled by log2(e): crf step then needs only exp2(e).
    const float LOG2E = 1.4426950408889634f;
    float2* e2 = reinterpret_cast<float2*>(E + (size_t)(R0 + t) * CN);
#pragma unroll
    for (int a = 0; a < CN / 2; ++a)
        e2[a] = make_float2(acc[2 * a] * LOG2E, acc[2 * a + 1] * LOG2E);

    // unnorm contribution of this row (natural-log units, from registers).
    // Static select avoids runtime-indexing acc[] into scratch (rule #20).
    int y = labels[R0 + t];
    float us = acc[0];
#pragma unroll
    for (int a = 1; a < CN; ++a) us = (y == a) ? acc[a] : us;
    if ((R0 + t) & (CM - 1)) {  // not a sequence start
        int yp = labels[R0 + t - 1];
        us += T[yp * CN + y];
    }
#pragma unroll
    for (int off = 32; off > 0; off >>= 1) us += __shfl_xor(us, off, 64);
    if ((t & 63) == 0) rsum[t >> 6] = us;
    __syncthreads();
    if (t == 0)
        atomicAdd(out, (rsum[0] + rsum[1] + rsum[2] + rsum[3]) * (1.f / CB));
}

// ---------------------------------------------------------------------------
// Kernel 2: per-sequence forward recursion, one wave per sequence.
// Layout: lane a in [0,26) holds f[a] (lanes 26..63 duplicate a=25).
// Round-4 change: all 26 v_readlane broadcasts issue as one group, then a
// sched_barrier(0) fence, then all 26 FMAs. Round-3 counters (244 cyc/step
// at VALUBusy 18% vs ~114 issue-cycles of work) match the VALU-writes-SGPR
// -> VALU-reads-SGPR hazard being paid per rdl->fma pair; grouping hides it
// (first fma reads an SGPR written 52 issue-cycles earlier).
// E prefetched 16 steps deep; exact power-of-2 renorm every 8 steps.
// ---------------------------------------------------------------------------
__global__ __launch_bounds__(64) void crf_forward_kernel(
    const float* __restrict__ E, const float* __restrict__ T,
    float* __restrict__ out) {
    const int s = blockIdx.x;
    const int l = threadIdx.x;
    const float LN2 = 0.6931471805599453f;

    const int a = (l < CN) ? l : (CN - 1);

    float AT[CN];  // AT[b] = exp(T[b,a])
#pragma unroll
    for (int b = 0; b < CN; ++b) AT[b] = expf(T[b * CN + a]);

    const float* __restrict__ Eb = E + (size_t)s * CM * CN + a;

    float f = fexp2(Eb[0]);  // E already in log2 units
    float L = 0.f;

    float epf[16];  // steps 1..16
#pragma unroll
    for (int k = 0; k < 16; ++k) epf[k] = Eb[(size_t)(1 + k) * CN];
    const float* pf = Eb + (size_t)17 * CN;  // next step to prefetch

    auto step = [&](float e_cur, bool renorm) {
        float p = fexp2(e_cur);  // off the f-dependency chain, before fence
        float fb[CN];
#pragma unroll
        for (int b = 0; b < CN; ++b) fb[b] = rdl_f(f, b);
        __builtin_amdgcn_sched_barrier(0);  // keep rdl group before fma group
        float d0 = 0.f, d1 = 0.f, d2 = 0.f, d3 = 0.f;
#pragma unroll
        for (int b = 0; b < 24; b += 4) {
            d0 = fmaf(AT[b + 0], fb[b + 0], d0);
            d1 = fmaf(AT[b + 1], fb[b + 1], d1);
            d2 = fmaf(AT[b + 2], fb[b + 2], d2);
            d3 = fmaf(AT[b + 3], fb[b + 3], d3);
        }
        d0 = fmaf(AT[24], fb[24], d0);
        d1 = fmaf(AT[25], fb[25], d1);
        f = p * ((d0 + d1) + (d2 + d3));
        if (renorm) {  // exact power-of-2: no rounding error
            float fr = rfl_f(f);
            int k2 = (int)((__float_as_uint(fr) >> 23) & 255) - 127;
            f = ldexpf(f, -k2);
            L += (float)k2;
        }
    };

    // Main: 62 x 16 steps = steps 1..992; during it, prefetch steps
    // 17+16*it .. 32+16*it (max 1008 at it=61, always in-bounds).
    for (int it = 0; it < 62; ++it) {
#pragma unroll
        for (int k = 0; k < 16; ++k) {
            float e_cur = epf[k];
            epf[k] = pf[(size_t)k * CN];  // imm-offset loads, one base ptr
            step(e_cur, (k & 7) == 7);
        }
        pf += 16 * CN;
    }
    // Mid-tail: steps 993..1008 (renorm at 1000, 1008), clamped prefetch
    // of steps 1009..1023 (epf[15] clamps to 1023, never consumed).
#pragma unroll
    for (int k = 0; k < 16; ++k) {
        float e_cur = epf[k];
        int nx = (1009 + k > CM - 1) ? (CM - 1) : (1009 + k);
        epf[k] = Eb[(size_t)nx * CN];
        step(e_cur, (k & 7) == 7);
    }
    // End-tail: steps 1009..1023 (15 steps), renorm at 1016 (k==7) so the
    // unrenormalized run never exceeds 8 steps.
#pragma unroll
    for (int k = 0; k < 15; ++k) step(epf[k], k == 7);

    // logZ = ln2 * (L + log2(sum_a f[a]))
    float fv = (l < CN) ? f : 0.f;
#pragma unroll
    for (int off = 32; off > 0; off >>= 1) fv += __shfl_xor(fv, off, 64);
    float logZ = LN2 * (L + flog2(fv));
    if (l == 0) atomicAdd(out, -logZ * (1.f / (float)CB));
}

extern "C" void kernel_launch(void* const* d_in, const int* in_sizes, int n_in,
                              void* d_out, int out_size, void* d_ws,
                              size_t ws_size, hipStream_t stream) {
    const float* X = (const float*)d_in[0];   // [B, M, D]
    const int* labels = (const int*)d_in[1];  // [B, M]
    const float* W = (const float*)d_in[2];   // [N, D]
    const float* T = (const float*)d_in[3];   // [N, N]
    float* out = (float*)d_out;               // scalar
    float* E = (float*)d_ws;                  // [B*M, N] emissions (log2 units)

    hipMemsetAsync(d_out, 0, sizeof(float), stream);
    emit_kernel<<<(CB * CM) / 256, 256, 0, stream>>>(X, W, labels, T, E, out);
    crf_forward_kernel<<<CB, 64, 0, stream>>>(E, T, out);
}

// Round 6
// 299.764 us; speedup vs baseline: 1.1607x; 1.1607x over previous
//
#include <hip/hip_runtime.h>

// Problem constants (CRF: B=256 seqs, M=1024 steps, D=128 feat, N=26 labels)
#define CB 256
#define CM 1024
#define CD 128
#define CN 26

typedef __attribute__((ext_vector_type(2))) float f32x2;

__device__ inline float rfl_f(float x) {
    return __int_as_float(__builtin_amdgcn_readfirstlane(__float_as_int(x)));
}
__device__ inline float rdl_f(float x, int lane) {
#if __has_builtin(__builtin_amdgcn_readlane)
    return __int_as_float(__builtin_amdgcn_readlane(__float_as_int(x), lane));
#else
    return __shfl(x, lane, 64);
#endif
}
__device__ inline float fexp2(float x) {
#if __has_builtin(__builtin_amdgcn_exp2f)
    return __builtin_amdgcn_exp2f(x);
#else
    return exp2f(x);
#endif
}
__device__ inline float flog2(float x) {
#if __has_builtin(__builtin_amdgcn_logf)
    return __builtin_amdgcn_logf(x);
#else
    return log2f(x);
#endif
}
__device__ inline f32x2 fma2(f32x2 a, f32x2 b, f32x2 c) {
#if __has_builtin(__builtin_elementwise_fma)
    return __builtin_elementwise_fma(a, b, c);  // -> v_pk_fma_f32
#else
    f32x2 r;
    r[0] = fmaf(a[0], b[0], c[0]);
    r[1] = fmaf(a[1], b[1], c[1]);
    return r;
#endif
}

// ---------------------------------------------------------------------------
// Kernel 1: emissions E[r, a] = log2(e) * dot(X[r, :], W[a, :])
//   + fused unnorm term: usum = sum_i e[i,y_i] + sum_i T[y_{i-1},y_i]
// Round-6 change: NO LDS staging, no barriers. Each thread streams its own
// X row straight into registers (32 dwordx4, ping-pong 2x32-float chunks);
// round-5 accounting showed the barrier-phased LDS structure cost ~75 us
// over the 21 us BW floor while FMA issue is only ~11 us. W stays on the
// s_load/K$ path (round-3 win). Per-lane 64B-line reuse (j, j+4, ...) is
// within ~200 cycles -> L2-covered; no L1 dependence.
// ---------------------------------------------------------------------------
__global__ __launch_bounds__(256) void emit_kernel(
    const float* __restrict__ X, const float* __restrict__ W,
    const int* __restrict__ labels, const float* __restrict__ T,
    float* __restrict__ E, float* __restrict__ out) {
    const int t = threadIdx.x;
    const int row = blockIdx.x * 256 + t;
    const float4* __restrict__ x4 =
        reinterpret_cast<const float4*>(X + (size_t)row * CD);

    f32x2 acc2[CN];
#pragma unroll
    for (int a = 0; a < CN; ++a) acc2[a] = (f32x2){0.f, 0.f};

    f32x2 xa[16], xb[16];
#pragma unroll
    for (int jj = 0; jj < 8; ++jj)  // chunk 0 -> xa
        *reinterpret_cast<float4*>(&xa[jj * 2]) = x4[jj];

#pragma unroll
    for (int c = 0; c < 4; ++c) {  // four 32-col chunks, register ping-pong
        f32x2* cur = (c & 1) ? xb : xa;
        f32x2* nxt = (c & 1) ? xa : xb;
        if (c < 3) {
#pragma unroll
            for (int jj = 0; jj < 8; ++jj)  // prefetch next chunk
                *reinterpret_cast<float4*>(&nxt[jj * 2]) = x4[(c + 1) * 8 + jj];
        }
#pragma unroll
        for (int a = 0; a < CN; ++a) {
            // wave-uniform -> s_load from K$
            const f32x2* wp =
                reinterpret_cast<const f32x2*>(W + a * CD + c * 32);
#pragma unroll
            for (int jj = 0; jj < 16; ++jj)
                acc2[a] = fma2(cur[jj], wp[jj], acc2[a]);
        }
    }

    float acc[CN];
#pragma unroll
    for (int a = 0; a < CN; ++a) acc[a] = acc2[a][0] + acc2[a][1];

    // Store E pre-scaled by log2(e): crf step then needs only exp2(e).
    const float LOG2E = 1.4426950408889634f;
    float2* e2 = reinterpret_cast<float2*>(E + (size_t)row * CN);
#pragma unroll
    for (int a = 0; a < CN / 2; ++a)
        e2[a] = make_float2(acc[2 * a] * LOG2E, acc[2 * a + 1] * LOG2E);

    // unnorm contribution of this row (natural-log units, from registers).
    int y = labels[row];
    float us = acc[0];
#pragma unroll
    for (int a = 1; a < CN; ++a) us = (y == a) ? acc[a] : us;
    if (row & (CM - 1)) {  // not a sequence start
        int yp = labels[row - 1];
        us += T[yp * CN + y];
    }
#pragma unroll
    for (int off = 32; off > 0; off >>= 1) us += __shfl_xor(us, off, 64);
    __shared__ float rsum[4];
    if ((t & 63) == 0) rsum[t >> 6] = us;
    __syncthreads();
    if (t == 0)
        atomicAdd(out, (rsum[0] + rsum[1] + rsum[2] + rsum[3]) * (1.f / CB));
}

// ---------------------------------------------------------------------------
// Kernel 2: forward/backward half-chains — round-6 structural change.
// The step map f -> diag(p_i) * A^T f is linear, so
//   Z = sum_a f_511[a] * beta_511[a]
// with f the forward messages (rows 0..511) and beta the backward messages
// (rows 1023..512). The two 512-step chains are INDEPENDENT -> 512 blocks,
// 2 waves/CU, halving the exposed serial latency that bounds this kernel
// (round 3/5: ~244-270 cyc/step, VALUBusy ~17%, occupancy 2.8%).
// Interface storage reuses already-consumed E rows:
//   forward : f -> E[s][0][:],    L_f -> E[s][1][0]     (block read them first)
//   backward: b -> E[s][1023][:], L_b -> E[s][1022][0]
// Step form = round-3 interleaved rdl->fma (round-5's grouped form was
// slower; reverted). 8-deep E prefetch; exact pow-2 renorm every 8 steps;
// final renorm before store bounds the combine product by ~2^60.
// ---------------------------------------------------------------------------
template <bool BWD>
__device__ void run_half(float* __restrict__ base, const float* __restrict__ T,
                         int a, int l) {
    float AT[CN];
#pragma unroll
    for (int k = 0; k < CN; ++k)
        AT[k] = expf(BWD ? T[a * CN + k] : T[k * CN + a]);

    const int S = BWD ? -CN : CN;  // row stride (descending for backward)
    const float* __restrict__ Eb = base + (BWD ? (size_t)1023 * CN : 0) + a;

    float f, L = 0.f;
    float epf[8];
    const float* pf;
    if (BWD) {
        f = 1.f;  // beta_1023 init; first step consumes row 1023 (offset 0)
#pragma unroll
        for (int k = 0; k < 8; ++k) epf[k] = Eb[k * S];
        pf = Eb + 8 * S;
    } else {
        f = fexp2(Eb[0]);  // consumes row 0 (E in log2 units)
#pragma unroll
        for (int k = 0; k < 8; ++k) epf[k] = Eb[(1 + k) * S];
        pf = Eb + 9 * S;
    }

    auto step = [&](float e_cur, bool renorm) {
        float p = fexp2(e_cur);
        float x = BWD ? p * f : f;  // backward folds p in BEFORE broadcast
        float d0 = 0.f, d1 = 0.f, d2 = 0.f, d3 = 0.f;
#pragma unroll
        for (int b = 0; b < 24; b += 4) {
            d0 = fmaf(AT[b + 0], rdl_f(x, b + 0), d0);
            d1 = fmaf(AT[b + 1], rdl_f(x, b + 1), d1);
            d2 = fmaf(AT[b + 2], rdl_f(x, b + 2), d2);
            d3 = fmaf(AT[b + 3], rdl_f(x, b + 3), d3);
        }
        d0 = fmaf(AT[24], rdl_f(x, 24), d0);
        d1 = fmaf(AT[25], rdl_f(x, 25), d1);
        float d = (d0 + d1) + (d2 + d3);
        f = BWD ? d : p * d;
        if (renorm) {  // exact power-of-2: no rounding error
            float fr = rfl_f(f);
            int k2 = (int)((__float_as_uint(fr) >> 23) & 255) - 127;
            f = ldexpf(f, -k2);
            L += (float)k2;
        }
    };

    // Main: forward 62x8 (steps = rows 1..496), backward 63x8 (t = 0..503).
    const int NMAIN = BWD ? 63 : 62;
    for (int it = 0; it < NMAIN; ++it) {
#pragma unroll
        for (int k = 0; k < 8; ++k) {
            float e_cur = epf[k];
            epf[k] = pf[k * S];  // imm-offset loads (|k*416B| < 4 KB)
            step(e_cur, k == 7);
        }
        pf += 8 * S;
    }
    if (BWD) {
        // Tail: t = 504..511 (renorm at t=511, k==7).
#pragma unroll
        for (int k = 0; k < 8; ++k) step(epf[k], k == 7);
    } else {
        // Tail A: rows 497..504 (renorm at 504); prefetch rows 505..511.
#pragma unroll
        for (int k = 0; k < 8; ++k) {
            float e_cur = epf[k];
            if (k < 7) epf[k] = pf[k * S];
            step(e_cur, k == 7);
        }
        // Tail B: rows 505..511 (7 steps).
#pragma unroll
        for (int k = 0; k < 7; ++k) step(epf[k], false);
    }

    // Final exact renorm so stored components are O(2^0..2^60-ish) and the
    // combine product f*beta cannot overflow.
    {
        float fr = rfl_f(f);
        int k2 = (int)((__float_as_uint(fr) >> 23) & 255) - 127;
        f = ldexpf(f, -k2);
        L += (float)k2;
    }

    // Store interface (cells this block alone has already consumed).
    base[(BWD ? (size_t)1023 * CN : 0) + a] = f;  // lanes>=26 dup-write a=25
    if (l == 0) base[(BWD ? (size_t)1022 * CN : (size_t)CN)] = L;
}

__global__ __launch_bounds__(64) void crf_half_kernel(
    float* __restrict__ E, const float* __restrict__ T) {
    const int s = blockIdx.x >> 1;
    const int l = threadIdx.x;
    const int a = (l < CN) ? l : (CN - 1);
    float* base = E + (size_t)s * CM * CN;
    if (blockIdx.x & 1)
        run_half<true>(base, T, a, l);
    else
        run_half<false>(base, T, a, l);
}

// ---------------------------------------------------------------------------
// Kernel 3: combine — logZ_s = ln2 * (L_f + L_b + log2(sum_a f[a]*beta[a])).
// ---------------------------------------------------------------------------
__global__ __launch_bounds__(64) void crf_combine_kernel(
    const float* __restrict__ E, float* __restrict__ out) {
    const int s = blockIdx.x;
    const int l = threadIdx.x;
    const float LN2 = 0.6931471805599453f;
    const float* base = E + (size_t)s * CM * CN;

    float v = 0.f;
    if (l < CN) v = base[l] * base[(size_t)1023 * CN + l];
#pragma unroll
    for (int off = 32; off > 0; off >>= 1) v += __shfl_xor(v, off, 64);

    if (l == 0) {
        float Lf = base[CN];
        float Lb = base[(size_t)1022 * CN];
        float logZ = LN2 * (Lf + Lb + flog2(v));
        atomicAdd(out, -logZ * (1.f / (float)CB));
    }
}

extern "C" void kernel_launch(void* const* d_in, const int* in_sizes, int n_in,
                              void* d_out, int out_size, void* d_ws,
                              size_t ws_size, hipStream_t stream) {
    const float* X = (const float*)d_in[0];   // [B, M, D]
    const int* labels = (const int*)d_in[1];  // [B, M]
    const float* W = (const float*)d_in[2];   // [N, D]
    const float* T = (const float*)d_in[3];   // [N, N]
    float* out = (float*)d_out;               // scalar
    float* E = (float*)d_ws;                  // [B*M, N] emissions (log2 units)

    hipMemsetAsync(d_out, 0, sizeof(float), stream);
    emit_kernel<<<(CB * CM) / 256, 256, 0, stream>>>(X, W, labels, T, E, out);
    crf_half_kernel<<<CB * 2, 64, 0, stream>>>(E, T);
    crf_combine_kernel<<<CB, 64, 0, stream>>>(E, out);
}

// Round 7
// 294.815 us; speedup vs baseline: 1.1802x; 1.0168x over previous
//
#include <hip/hip_runtime.h>

// Problem constants (CRF: B=256 seqs, M=1024 steps, D=128 feat, N=26 labels)
#define CB 256
#define CM 1024
#define CD 128
#define CN 26

typedef __attribute__((ext_vector_type(2))) float f32x2;

__device__ inline float rfl_f(float x) {
    return __int_as_float(__builtin_amdgcn_readfirstlane(__float_as_int(x)));
}
__device__ inline float rdl_f(float x, int lane) {
#if __has_builtin(__builtin_amdgcn_readlane)
    return __int_as_float(__builtin_amdgcn_readlane(__float_as_int(x), lane));
#else
    return __shfl(x, lane, 64);
#endif
}
__device__ inline float fexp2(float x) {
#if __has_builtin(__builtin_amdgcn_exp2f)
    return __builtin_amdgcn_exp2f(x);
#else
    return exp2f(x);
#endif
}
__device__ inline float flog2(float x) {
#if __has_builtin(__builtin_amdgcn_logf)
    return __builtin_amdgcn_logf(x);
#else
    return log2f(x);
#endif
}
__device__ inline f32x2 fma2(f32x2 a, f32x2 b, f32x2 c) {
#if __has_builtin(__builtin_elementwise_fma)
    return __builtin_elementwise_fma(a, b, c);  // -> v_pk_fma_f32
#else
    f32x2 r;
    r[0] = fmaf(a[0], b[0], c[0]);
    r[1] = fmaf(a[1], b[1], c[1]);
    return r;
#endif
}

// ---------------------------------------------------------------------------
// Kernel 1: emissions E[r, a] = log2(e) * dot(X[r, :], W[a, :])
//   + fused unnorm term: usum = sum_i e[i,y_i] + sum_i T[y_{i-1},y_i]
// Round-7 change: fix the spill. Round-6 counters showed VGPR_Count=56
// against ~120 live registers (acc2 52 + ping-pong 64) and WRITE_SIZE
// 34.1 MB vs 27.3 MB of real output => ~7 MB scratch-spill writes. Fix:
// __launch_bounds__(256, 2) caps the allocator at 256 VGPRs (pool 512/SIMD
// / 2 waves), and the X ping-pong shrinks to 16-float chunks (cur+nxt = 32
// VGPRs) so live state ~100 VGPRs -> <=128 bucket, 16 waves/CU.
// W stays wave-uniform -> one s_load_dwordx16 per (a,chunk) from K$.
// ---------------------------------------------------------------------------
__global__ __launch_bounds__(256, 2) void emit_kernel(
    const float* __restrict__ X, const float* __restrict__ W,
    const int* __restrict__ labels, const float* __restrict__ T,
    float* __restrict__ E, float* __restrict__ out) {
    const int t = threadIdx.x;
    const int row = blockIdx.x * 256 + t;
    const float4* __restrict__ x4 =
        reinterpret_cast<const float4*>(X + (size_t)row * CD);

    f32x2 acc2[CN];
#pragma unroll
    for (int a = 0; a < CN; ++a) acc2[a] = (f32x2){0.f, 0.f};

    f32x2 xa[8], xb[8];  // 16-float chunks, register ping-pong (32 VGPRs)
#pragma unroll
    for (int q = 0; q < 4; ++q)  // chunk 0 -> xa
        *reinterpret_cast<float4*>(&xa[q * 2]) = x4[q];

#pragma unroll
    for (int c = 0; c < 8; ++c) {  // eight 16-col chunks of D=128
        f32x2* cur = (c & 1) ? xb : xa;
        f32x2* nxt = (c & 1) ? xa : xb;
        if (c < 7) {
#pragma unroll
            for (int q = 0; q < 4; ++q)  // prefetch next chunk
                *reinterpret_cast<float4*>(&nxt[q * 2]) = x4[(c + 1) * 4 + q];
        }
#pragma unroll
        for (int a = 0; a < CN; ++a) {
            // wave-uniform -> s_load_dwordx16 from K$
            const f32x2* wp =
                reinterpret_cast<const f32x2*>(W + a * CD + c * 16);
#pragma unroll
            for (int jj = 0; jj < 8; ++jj)
                acc2[a] = fma2(cur[jj], wp[jj], acc2[a]);
        }
    }

    float acc[CN];
#pragma unroll
    for (int a = 0; a < CN; ++a) acc[a] = acc2[a][0] + acc2[a][1];

    // Store E pre-scaled by log2(e): crf step then needs only exp2(e).
    const float LOG2E = 1.4426950408889634f;
    float2* e2 = reinterpret_cast<float2*>(E + (size_t)row * CN);
#pragma unroll
    for (int a = 0; a < CN / 2; ++a)
        e2[a] = make_float2(acc[2 * a] * LOG2E, acc[2 * a + 1] * LOG2E);

    // unnorm contribution of this row (natural-log units, from registers).
    int y = labels[row];
    float us = acc[0];
#pragma unroll
    for (int a = 1; a < CN; ++a) us = (y == a) ? acc[a] : us;
    if (row & (CM - 1)) {  // not a sequence start
        int yp = labels[row - 1];
        us += T[yp * CN + y];
    }
#pragma unroll
    for (int off = 32; off > 0; off >>= 1) us += __shfl_xor(us, off, 64);
    __shared__ float rsum[4];
    if ((t & 63) == 0) rsum[t >> 6] = us;
    __syncthreads();
    if (t == 0)
        atomicAdd(out, (rsum[0] + rsum[1] + rsum[2] + rsum[3]) * (1.f / CB));
}

// ---------------------------------------------------------------------------
// Kernel 2: forward/backward half-chains (round-6 win, unchanged).
// Z = sum_a f_511[a] * beta_511[a]; two independent 512-step chains per
// sequence -> 512 blocks. Interface reuses already-consumed E rows.
// ---------------------------------------------------------------------------
template <bool BWD>
__device__ void run_half(float* __restrict__ base, const float* __restrict__ T,
                         int a, int l) {
    float AT[CN];
#pragma unroll
    for (int k = 0; k < CN; ++k)
        AT[k] = expf(BWD ? T[a * CN + k] : T[k * CN + a]);

    const int S = BWD ? -CN : CN;  // row stride (descending for backward)
    const float* __restrict__ Eb = base + (BWD ? (size_t)1023 * CN : 0) + a;

    float f, L = 0.f;
    float epf[8];
    const float* pf;
    if (BWD) {
        f = 1.f;  // beta_1023 init; first step consumes row 1023 (offset 0)
#pragma unroll
        for (int k = 0; k < 8; ++k) epf[k] = Eb[k * S];
        pf = Eb + 8 * S;
    } else {
        f = fexp2(Eb[0]);  // consumes row 0 (E in log2 units)
#pragma unroll
        for (int k = 0; k < 8; ++k) epf[k] = Eb[(1 + k) * S];
        pf = Eb + 9 * S;
    }

    auto step = [&](float e_cur, bool renorm) {
        float p = fexp2(e_cur);
        float x = BWD ? p * f : f;  // backward folds p in BEFORE broadcast
        float d0 = 0.f, d1 = 0.f, d2 = 0.f, d3 = 0.f;
#pragma unroll
        for (int b = 0; b < 24; b += 4) {
            d0 = fmaf(AT[b + 0], rdl_f(x, b + 0), d0);
            d1 = fmaf(AT[b + 1], rdl_f(x, b + 1), d1);
            d2 = fmaf(AT[b + 2], rdl_f(x, b + 2), d2);
            d3 = fmaf(AT[b + 3], rdl_f(x, b + 3), d3);
        }
        d0 = fmaf(AT[24], rdl_f(x, 24), d0);
        d1 = fmaf(AT[25], rdl_f(x, 25), d1);
        float d = (d0 + d1) + (d2 + d3);
        f = BWD ? d : p * d;
        if (renorm) {  // exact power-of-2: no rounding error
            float fr = rfl_f(f);
            int k2 = (int)((__float_as_uint(fr) >> 23) & 255) - 127;
            f = ldexpf(f, -k2);
            L += (float)k2;
        }
    };

    // Main: forward 62x8 (steps = rows 1..496), backward 63x8 (t = 0..503).
    const int NMAIN = BWD ? 63 : 62;
    for (int it = 0; it < NMAIN; ++it) {
#pragma unroll
        for (int k = 0; k < 8; ++k) {
            float e_cur = epf[k];
            epf[k] = pf[k * S];  // imm-offset loads (|k*416B| < 4 KB)
            step(e_cur, k == 7);
        }
        pf += 8 * S;
    }
    if (BWD) {
        // Tail: t = 504..511 (renorm at t=511, k==7).
#pragma unroll
        for (int k = 0; k < 8; ++k) step(epf[k], k == 7);
    } else {
        // Tail A: rows 497..504 (renorm at 504); prefetch rows 505..511.
#pragma unroll
        for (int k = 0; k < 8; ++k) {
            float e_cur = epf[k];
            if (k < 7) epf[k] = pf[k * S];
            step(e_cur, k == 7);
        }
        // Tail B: rows 505..511 (7 steps).
#pragma unroll
        for (int k = 0; k < 7; ++k) step(epf[k], false);
    }

    // Final exact renorm so stored components are O(1) and the combine
    // product f*beta cannot overflow.
    {
        float fr = rfl_f(f);
        int k2 = (int)((__float_as_uint(fr) >> 23) & 255) - 127;
        f = ldexpf(f, -k2);
        L += (float)k2;
    }

    // Store interface (cells this block alone has already consumed).
    base[(BWD ? (size_t)1023 * CN : 0) + a] = f;  // lanes>=26 dup-write a=25
    if (l == 0) base[(BWD ? (size_t)1022 * CN : (size_t)CN)] = L;
}

__global__ __launch_bounds__(64) void crf_half_kernel(
    float* __restrict__ E, const float* __restrict__ T) {
    const int s = blockIdx.x >> 1;
    const int l = threadIdx.x;
    const int a = (l < CN) ? l : (CN - 1);
    float* base = E + (size_t)s * CM * CN;
    if (blockIdx.x & 1)
        run_half<true>(base, T, a, l);
    else
        run_half<false>(base, T, a, l);
}

// ---------------------------------------------------------------------------
// Kernel 3: combine — logZ_s = ln2 * (L_f + L_b + log2(sum_a f[a]*beta[a])).
// ---------------------------------------------------------------------------
__global__ __launch_bounds__(64) void crf_combine_kernel(
    const float* __restrict__ E, float* __restrict__ out) {
    const int s = blockIdx.x;
    const int l = threadIdx.x;
    const float LN2 = 0.6931471805599453f;
    const float* base = E + (size_t)s * CM * CN;

    float v = 0.f;
    if (l < CN) v = base[l] * base[(size_t)1023 * CN + l];
#pragma unroll
    for (int off = 32; off > 0; off >>= 1) v += __shfl_xor(v, off, 64);

    if (l == 0) {
        float Lf = base[CN];
        float Lb = base[(size_t)1022 * CN];
        float logZ = LN2 * (Lf + Lb + flog2(v));
        atomicAdd(out, -logZ * (1.f / (float)CB));
    }
}

extern "C" void kernel_launch(void* const* d_in, const int* in_sizes, int n_in,
                              void* d_out, int out_size, void* d_ws,
                              size_t ws_size, hipStream_t stream) {
    const float* X = (const float*)d_in[0];   // [B, M, D]
    const int* labels = (const int*)d_in[1];  // [B, M]
    const float* W = (const float*)d_in[2];   // [N, D]
    const float* T = (const float*)d_in[3];   // [N, N]
    float* out = (float*)d_out;               // scalar
    float* E = (float*)d_ws;                  // [B*M, N] emissions (log2 units)

    hipMemsetAsync(d_out, 0, sizeof(float), stream);
    emit_kernel<<<(CB * CM) / 256, 256, 0, stream>>>(X, W, labels, T, E, out);
    crf_half_kernel<<<CB * 2, 64, 0, stream>>>(E, T);
    crf_combine_kernel<<<CB, 64, 0, stream>>>(E, out);
}